// Round 1
// baseline (5747.925 us; speedup 1.0000x reference)
//
#include <hip/hip_runtime.h>
#include <cmath>

#define N_NODES 50000
#define N_EDGES 800000
#define NODE_DIM 128
#define EDGE_DIM 100
#define EMB_DIM 92
#define N_GRAPHS 256

__device__ __forceinline__ float softplus_f(float v) {
    return v > 20.0f ? v : log1pf(expf(v));
}
__device__ __forceinline__ float sigmoid_f(float v) {
    return 1.0f / (1.0f + expf(-v));
}
__device__ __forceinline__ void fma4(float4& a, const float4& w, float s) {
    a.x = fmaf(w.x, s, a.x);
    a.y = fmaf(w.y, s, a.y);
    a.z = fmaf(w.z, s, a.z);
    a.w = fmaf(w.w, s, a.w);
}

// ---------------------------------------------------------------- edge dist
__global__ void edge_d_kernel(const int* __restrict__ ei, const float* __restrict__ R,
                              float* __restrict__ d) {
    int e = blockIdx.x * blockDim.x + threadIdx.x;
    if (e >= N_EDGES) return;
    int s = ei[e];            // src
    int t = ei[N_EDGES + e];  // dst
    float dx = R[3 * s + 0] - R[3 * t + 0];
    float dy = R[3 * s + 1] - R[3 * t + 1];
    float dz = R[3 * s + 2] - R[3 * t + 2];
    d[e] = sqrtf(dx * dx + dy * dy + dz * dz);
}

// ---------------------------------------------------------------- embedding
// x = embedding[z] @ emb_w + emb_b   [N,128], K=92. 8 nodes per block.
__global__ void embed_kernel(const int* __restrict__ z, const float* __restrict__ emb,
                             const float* __restrict__ emb_w, const float* __restrict__ emb_b,
                             float* __restrict__ x) {
    __shared__ float er[EMB_DIM * 8];  // [k][j] transposed
    __shared__ int zi[8];
    int base = blockIdx.x * 8;
    int t = threadIdx.x;  // 0..127
    if (t < 8) zi[t] = z[base + t];
    __syncthreads();
    for (int idx = t; idx < EMB_DIM * 8; idx += 128) {
        int k = idx >> 3, j = idx & 7;
        er[idx] = emb[zi[j] * EMB_DIM + k];
    }
    __syncthreads();
    float acc[8];
    float bb = emb_b[t];
#pragma unroll
    for (int j = 0; j < 8; j++) acc[j] = bb;
    for (int k = 0; k < EMB_DIM; k++) {
        float w = emb_w[k * NODE_DIM + t];
        float4 ja = *(const float4*)&er[k * 8];
        float4 jb = *(const float4*)&er[k * 8 + 4];
        acc[0] = fmaf(w, ja.x, acc[0]); acc[1] = fmaf(w, ja.y, acc[1]);
        acc[2] = fmaf(w, ja.z, acc[2]); acc[3] = fmaf(w, ja.w, acc[3]);
        acc[4] = fmaf(w, jb.x, acc[4]); acc[5] = fmaf(w, jb.y, acc[5]);
        acc[6] = fmaf(w, jb.z, acc[6]); acc[7] = fmaf(w, jb.w, acc[7]);
    }
#pragma unroll
    for (int j = 0; j < 8; j++) x[(base + j) * NODE_DIM + t] = acc[j];
}

// ---------------------------------------------------------------- node pre-GEMM
// P1 = x @ W[0:128,:] + b (dst side),  P2 = x @ W[128:256,:] (src side). 8 nodes/block.
__global__ void node_pre_kernel(const float* __restrict__ x, const float* __restrict__ Wl,
                                const float* __restrict__ bl,
                                float* __restrict__ P1, float* __restrict__ P2) {
    __shared__ float xs[NODE_DIM * 8];  // [k][j]
    int base = blockIdx.x * 8;
    int t = threadIdx.x;  // 0..255 = output channel
    for (int idx = t; idx < NODE_DIM * 8; idx += 256) {
        int j = idx >> 7, k = idx & 127;
        xs[k * 8 + j] = x[(base + j) * NODE_DIM + k];
    }
    __syncthreads();
    float a1[8], a2[8];
#pragma unroll
    for (int j = 0; j < 8; j++) { a1[j] = 0.f; a2[j] = 0.f; }
    const float* W1 = Wl;
    const float* W2 = Wl + NODE_DIM * 256;
    for (int k = 0; k < NODE_DIM; k++) {
        float w1 = W1[k * 256 + t];
        float w2 = W2[k * 256 + t];
        float4 ja = *(const float4*)&xs[k * 8];
        float4 jb = *(const float4*)&xs[k * 8 + 4];
        a1[0] = fmaf(w1, ja.x, a1[0]); a1[1] = fmaf(w1, ja.y, a1[1]);
        a1[2] = fmaf(w1, ja.z, a1[2]); a1[3] = fmaf(w1, ja.w, a1[3]);
        a1[4] = fmaf(w1, jb.x, a1[4]); a1[5] = fmaf(w1, jb.y, a1[5]);
        a1[6] = fmaf(w1, jb.z, a1[6]); a1[7] = fmaf(w1, jb.w, a1[7]);
        a2[0] = fmaf(w2, ja.x, a2[0]); a2[1] = fmaf(w2, ja.y, a2[1]);
        a2[2] = fmaf(w2, ja.z, a2[2]); a2[3] = fmaf(w2, ja.w, a2[3]);
        a2[4] = fmaf(w2, jb.x, a2[4]); a2[5] = fmaf(w2, jb.y, a2[5]);
        a2[6] = fmaf(w2, jb.z, a2[6]); a2[7] = fmaf(w2, jb.w, a2[7]);
    }
    float bb = bl[t];
#pragma unroll
    for (int j = 0; j < 8; j++) {
        P1[(base + j) * 256 + t] = a1[j] + bb;
        P2[(base + j) * 256 + t] = a2[j];
    }
}

// ---------------------------------------------------------------- edge message + scatter
// zc[e] = P1[dst] + P2[src] + edge_attr(d[e]) @ We ; msg = sig(z1)*softplus(z2);
// atomicAdd into agg[dst]. 32 edges per block-iteration; W staged in LDS in 2 k-chunks.
#define EG 32
#define KCH 50
__global__ __launch_bounds__(256, 2) void edge_msg_kernel(
    const float* __restrict__ d, const int* __restrict__ ei,
    const float* __restrict__ P1, const float* __restrict__ P2,
    const float* __restrict__ We,  // rows [100][256] of conv weights (edge_attr part)
    float* __restrict__ agg) {
    __shared__ float Wlds[KCH * 256];    // 51200 B
    __shared__ float ea[EDGE_DIM * EG];  // 12800 B
    const float spacing = 6.0f / 99.0f;
    const float coeff = -0.5f / (spacing * spacing);
    int t = threadIdx.x;
    int wv = t >> 6;     // wave 0..3
    int lane = t & 63;
    int h = lane >> 5;   // half 0/1 -> edge sub-group
    int q = lane & 31;   // channel quad: z1 ch 4q..4q+3, z2 ch 128+4q..
    int nGroups = N_EDGES / EG;  // 25000
    for (int g = blockIdx.x; g < nGroups; g += gridDim.x) {
        int base = g * EG;
        __syncthreads();  // previous iteration's LDS readers done
        // stage edge_attr for 32 edges: ea[k][j]
        for (int idx = t; idx < EDGE_DIM * EG; idx += 256) {
            int k = idx >> 5, j = idx & 31;
            float dd = d[base + j];
            float df = dd - (float)k * spacing;
            ea[idx] = expf(coeff * df * df);
        }
        // per-lane 4 edges: init accumulators with gathered P1[dst]+P2[src]
        int e0 = base + wv * 8 + h * 4;
        int srcs[4], dsts[4];
        float4 acc1[4], acc2[4];
#pragma unroll
        for (int m = 0; m < 4; m++) {
            int e = e0 + m;
            srcs[m] = ei[e];
            dsts[m] = ei[N_EDGES + e];
            float4 p1a = *(const float4*)&P1[dsts[m] * 256 + 4 * q];
            float4 p2a = *(const float4*)&P2[srcs[m] * 256 + 4 * q];
            float4 p1b = *(const float4*)&P1[dsts[m] * 256 + 128 + 4 * q];
            float4 p2b = *(const float4*)&P2[srcs[m] * 256 + 128 + 4 * q];
            acc1[m] = make_float4(p1a.x + p2a.x, p1a.y + p2a.y, p1a.z + p2a.z, p1a.w + p2a.w);
            acc2[m] = make_float4(p1b.x + p2b.x, p1b.y + p2b.y, p1b.z + p2b.z, p1b.w + p2b.w);
        }
        for (int ch = 0; ch < 2; ch++) {
            __syncthreads();
            {  // stage W chunk: KCH*256 floats = 3200 float4
                const float4* src4 = (const float4*)(We + ch * (KCH * 256));
                float4* dst4 = (float4*)Wlds;
                for (int idx = t; idx < KCH * 64; idx += 256) dst4[idx] = src4[idx];
            }
            __syncthreads();
            for (int kc = 0; kc < KCH; kc++) {
                int k = ch * KCH + kc;
                float4 w1 = *(const float4*)&Wlds[kc * 256 + 4 * q];
                float4 w2 = *(const float4*)&Wlds[kc * 256 + 128 + 4 * q];
                float4 e4 = *(const float4*)&ea[k * EG + wv * 8 + h * 4];
                fma4(acc1[0], w1, e4.x); fma4(acc1[1], w1, e4.y);
                fma4(acc1[2], w1, e4.z); fma4(acc1[3], w1, e4.w);
                fma4(acc2[0], w2, e4.x); fma4(acc2[1], w2, e4.y);
                fma4(acc2[2], w2, e4.z); fma4(acc2[3], w2, e4.w);
            }
        }
        // epilogue: msg = sigmoid(z1)*softplus(z2), scatter-add to agg[dst]
#pragma unroll
        for (int m = 0; m < 4; m++) {
            float4 z1 = acc1[m], z2 = acc2[m];
            float4 msg;
            msg.x = sigmoid_f(z1.x) * softplus_f(z2.x);
            msg.y = sigmoid_f(z1.y) * softplus_f(z2.y);
            msg.z = sigmoid_f(z1.z) * softplus_f(z2.z);
            msg.w = sigmoid_f(z1.w) * softplus_f(z2.w);
            float* ag = agg + dsts[m] * NODE_DIM + 4 * q;
            atomicAdd(ag + 0, msg.x);
            atomicAdd(ag + 1, msg.y);
            atomicAdd(ag + 2, msg.z);
            atomicAdd(ag + 3, msg.w);
        }
    }
}

// ---------------------------------------------------------------- layernorm + residual + softplus
__global__ void ln_kernel(const float* __restrict__ agg, const float* __restrict__ g,
                          const float* __restrict__ b, float* __restrict__ x) {
    int n = blockIdx.x, c = threadIdx.x;
    __shared__ float s1[128], s2[128];
    float a = agg[n * 128 + c];
    s1[c] = a;
    s2[c] = a * a;
    __syncthreads();
    for (int off = 64; off > 0; off >>= 1) {
        if (c < off) { s1[c] += s1[c + off]; s2[c] += s2[c + off]; }
        __syncthreads();
    }
    float mu = s1[0] * (1.0f / 128.0f);
    float var = s2[0] * (1.0f / 128.0f) - mu * mu;
    float rstd = rsqrtf(fmaxf(var, 0.f) + 1e-5f);
    float xv = x[n * 128 + c];
    x[n * 128 + c] = softplus_f((a - mu) * rstd * g[c] + b[c] + xv);
}

// ---------------------------------------------------------------- global mean pool (scatter)
__global__ void pool_kernel(const float* __restrict__ x, const int* __restrict__ batch,
                            float* __restrict__ mol, float* __restrict__ cnt) {
    int i = blockIdx.x * blockDim.x + threadIdx.x;
    if (i >= N_NODES * 128) return;
    int n = i >> 7, c = i & 127;
    int g = batch[n];
    atomicAdd(&mol[g * 128 + c], x[i]);
    if (c == 0) atomicAdd(&cnt[g], 1.0f);
}

// ---------------------------------------------------------------- MLP head
__global__ void head_kernel(const float* __restrict__ mol, const float* __restrict__ cnt,
                            const float* __restrict__ cfc_w, const float* __restrict__ cfc_b,
                            const float* __restrict__ fc_w, const float* __restrict__ fc_b,
                            const float* __restrict__ out_w, const float* __restrict__ out_b,
                            float* __restrict__ out) {
    int g = blockIdx.x, c = threadIdx.x;
    __shared__ float h[128], h2[128];
    float denom = fmaxf(cnt[g], 1.0f);
    h[c] = mol[g * 128 + c] / denom;
    __syncthreads();
    float acc = cfc_b[c];
    for (int k = 0; k < 128; k++) acc = fmaf(h[k], cfc_w[k * 128 + c], acc);
    h2[c] = softplus_f(acc);
    __syncthreads();
    for (int l = 0; l < 2; l++) {
        const float* W = fc_w + l * 128 * 128;
        acc = fc_b[l * 128 + c];
        for (int k = 0; k < 128; k++) acc = fmaf(h2[k], W[k * 128 + c], acc);
        __syncthreads();
        h2[c] = softplus_f(acc);
        __syncthreads();
    }
    h[c] = h2[c] * out_w[c];
    __syncthreads();
    for (int off = 64; off > 0; off >>= 1) {
        if (c < off) h[c] += h[c + off];
        __syncthreads();
    }
    if (c == 0) out[g] = h[0] + out_b[0];
}

// ---------------------------------------------------------------- launcher
extern "C" void kernel_launch(void* const* d_in, const int* in_sizes, int n_in,
                              void* d_out, int out_size, void* d_ws, size_t ws_size,
                              hipStream_t stream) {
    const int*   z      = (const int*)d_in[0];
    const float* R      = (const float*)d_in[1];
    const int*   ei     = (const int*)d_in[2];
    const int*   batch  = (const int*)d_in[3];
    const float* emb    = (const float*)d_in[4];
    const float* emb_w  = (const float*)d_in[5];
    const float* emb_b  = (const float*)d_in[6];
    const float* conv_w = (const float*)d_in[7];
    const float* conv_b = (const float*)d_in[8];
    const float* ln_g   = (const float*)d_in[9];
    const float* ln_b   = (const float*)d_in[10];
    const float* cfc_w  = (const float*)d_in[11];
    const float* cfc_b  = (const float*)d_in[12];
    const float* fc_w   = (const float*)d_in[13];
    const float* fc_b   = (const float*)d_in[14];
    const float* out_w  = (const float*)d_in[15];
    const float* out_b  = (const float*)d_in[16];
    float* out = (float*)d_out;

    float* ws   = (float*)d_ws;
    float* dbuf = ws;                  // 800,000
    float* x    = dbuf + 800000;       // 6,400,000
    float* agg  = x + 6400000;         // 6,400,000
    float* P1   = agg + 6400000;       // 12,800,000
    float* P2   = P1 + 12800000;       // 12,800,000
    float* mol  = P2 + 12800000;       // 32,768
    float* cntv = mol + 32768;         // 256

    edge_d_kernel<<<(N_EDGES + 255) / 256, 256, 0, stream>>>(ei, R, dbuf);
    embed_kernel<<<N_NODES / 8, 128, 0, stream>>>(z, emb, emb_w, emb_b, x);
    for (int l = 0; l < 3; l++) {
        const float* Wl = conv_w + (size_t)l * 356 * 256;
        node_pre_kernel<<<N_NODES / 8, 256, 0, stream>>>(x, Wl, conv_b + l * 256, P1, P2);
        hipMemsetAsync(agg, 0, (size_t)6400000 * 4, stream);
        edge_msg_kernel<<<2048, 256, 0, stream>>>(dbuf, ei, P1, P2, Wl + 256 * 256, agg);
        ln_kernel<<<N_NODES, 128, 0, stream>>>(agg, ln_g + l * 128, ln_b + l * 128, x);
    }
    hipMemsetAsync(mol, 0, (size_t)(32768 + 256) * 4, stream);
    pool_kernel<<<(N_NODES * 128 + 255) / 256, 256, 0, stream>>>(x, batch, mol, cntv);
    head_kernel<<<N_GRAPHS, 128, 0, stream>>>(mol, cntv, cfc_w, cfc_b, fc_w, fc_b,
                                              out_w, out_b, out);
}